// Round 5
// baseline (804.847 us; speedup 1.0000x reference)
//
#include <hip/hip_runtime.h>

typedef unsigned long long u64;

// B = 64 == wavefront size; lane = batch index throughout.
// Groups of 64 destination nodes; ngroups = ceil(N/64) (<= 511 assumed).
// Pipeline: prep    (x -> xT[N,64] transpose; zero group counters)
//           hist    (per-block LDS histogram of group counters)
//           scan    (1 block: group counts -> goff[ngroups+1], gcur)
//           scatter (bucket sort by dst-group; LDS-staged run-coalesced flush)
//           reduce  (1 block/group, 16 waves; LDS-staged records break the
//                    dependent chain; 8-deep gather ILP; ds_add_f32 accumulate)

__global__ void prep_kernel(const float* __restrict__ x, float* __restrict__ xT,
                            int* __restrict__ gcnt, int N, int ngroups) {
    __shared__ float tile[64][65];
    int n0 = blockIdx.x * 64;
    int tid = threadIdx.x;
    for (int lin = tid; lin < 64 * 64; lin += 256) {
        int nl = lin & 63, b = lin >> 6;
        int n = n0 + nl;
        tile[b][nl] = (n < N) ? x[(long)b * N + n] : 0.f;
    }
    __syncthreads();
    for (int lin = tid; lin < 64 * 64; lin += 256) {
        int b = lin & 63, nl = lin >> 6;
        int n = n0 + nl;
        if (n < N) xT[(long)n * 64 + b] = tile[b][nl];
    }
    if (blockIdx.x == 0) {
        for (int i = tid; i <= ngroups; i += 256) gcnt[i] = 0;
    }
}

__global__ __launch_bounds__(256) void hist_kernel(const int* __restrict__ dst,
                                                   int* __restrict__ gcnt,
                                                   int E4, int ngroups) {
    __shared__ int h[512];
    int tid = threadIdx.x;
    for (int i = tid; i < ngroups; i += 256) h[i] = 0;
    __syncthreads();
    int base = blockIdx.x * 512;
#pragma unroll
    for (int k = 0; k < 2; ++k) {
        int i4 = base + k * 256 + tid;
        if (i4 < E4) {
            int4 d = ((const int4*)dst)[i4];
            atomicAdd(&h[d.x >> 6], 1);
            atomicAdd(&h[d.y >> 6], 1);
            atomicAdd(&h[d.z >> 6], 1);
            atomicAdd(&h[d.w >> 6], 1);
        }
    }
    __syncthreads();
    for (int i = tid; i < ngroups; i += 256) {
        if (h[i]) atomicAdd(&gcnt[i], h[i]);
    }
}

__global__ __launch_bounds__(512) void scan_kernel(const int* __restrict__ gcnt,
                                                   int* __restrict__ goff,
                                                   int* __restrict__ gcur,
                                                   int ngroups, int E) {
    __shared__ int sm[512];
    int t = threadIdx.x;
    int c = (t < ngroups) ? gcnt[t] : 0;
    sm[t] = c;
    __syncthreads();
    for (int d = 1; d < 512; d <<= 1) {
        int v = sm[t];
        if (t >= d) v += sm[t - d];
        __syncthreads();
        sm[t] = v;
        __syncthreads();
    }
    if (t < ngroups) {
        int ex = sm[t] - c;
        goff[t] = ex;
        gcur[t] = ex;
    }
    if (t == ngroups) goff[t] = E;
}

#define TILE 4096  // 512 threads * 8 edges

__global__ __launch_bounds__(512) void scatter_kernel(
        const float* __restrict__ adj, const float* __restrict__ w,
        const int* __restrict__ src, const int* __restrict__ dst,
        int* __restrict__ gcur, u64* __restrict__ packed, int E, int ngroups) {
    __shared__ int cnt[512];
    __shared__ int ofs[512];
    __shared__ int gbase[512];
    __shared__ int sm[512];
    __shared__ u64 staged[TILE];
    __shared__ unsigned short gof[TILE];

    int t = threadIdx.x;
    int base = blockIdx.x * TILE;
    for (int i = t; i <= ngroups; i += 512) cnt[i] = 0;
    __syncthreads();

    u64 pk[8]; int gk[8]; int rk[8];
#pragma unroll
    for (int k = 0; k < 8; ++k) {
        int e = base + k * 512 + t;
        int g; u64 p;
        if (e < E) {
            int d = dst[e];
            float c = adj[e] * w[e];
            g = d >> 6;
            p = ((u64)__float_as_uint(c) << 32)
              | (u64)(((unsigned int)src[e] << 6) | (unsigned int)(d & 63));
        } else {
            g = ngroups; p = 0;
        }
        pk[k] = p; gk[k] = g;
        rk[k] = atomicAdd(&cnt[g], 1);
    }
    __syncthreads();

    int c = (t <= ngroups) ? cnt[t] : 0;
    sm[t] = c;
    __syncthreads();
    for (int d = 1; d < 512; d <<= 1) {
        int v = sm[t];
        if (t >= d) v += sm[t - d];
        __syncthreads();
        sm[t] = v;
        __syncthreads();
    }
    ofs[t] = sm[t] - c;
    if (t < ngroups && c > 0) gbase[t] = atomicAdd(&gcur[t], c);
    __syncthreads();

#pragma unroll
    for (int k = 0; k < 8; ++k) {
        int pos = ofs[gk[k]] + rk[k];
        staged[pos] = pk[k];
        gof[pos] = (unsigned short)gk[k];
    }
    __syncthreads();

#pragma unroll
    for (int k = 0; k < 8; ++k) {
        int i = k * 512 + t;
        int g = gof[i];
        if (g < ngroups) packed[gbase[g] + (i - ofs[g])] = staged[i];
    }
}

#define STAGE 2048  // records staged in LDS per tile

__global__ __launch_bounds__(1024) void reduce_kernel(
        const int* __restrict__ goff, const u64* __restrict__ packed,
        const float* __restrict__ xT, const float* __restrict__ x,
        const float* __restrict__ self_w, const float* __restrict__ bias,
        float* __restrict__ out, int N) {
    __shared__ float acc[64 * 65];      // [dstLocal][b], pitch 65 -> 2-way banks (free)
    __shared__ u64 stage[STAGE];        // 16 KB record staging
    int tid = threadIdx.x;
    int wave = tid >> 6;                // 0..15
    int lane = tid & 63;                // batch index
    int g = blockIdx.x;
    for (int i = tid; i < 64 * 65; i += 1024) acc[i] = 0.f;
    int s = goff[g], e = goff[g + 1];
    __syncthreads();

    for (int base = s; base < e; base += STAGE) {
        int m = min(STAGE, e - base);
        // cooperative coalesced load of records -> LDS (no dependent chain)
        for (int i = tid; i < m; i += 1024) stage[i] = packed[base + i];
        __syncthreads();
        // each wave takes a contiguous slice; records read wave-uniform (broadcast)
        int per = (m + 15) >> 4;
        int r0 = wave * per;
        int r1 = min(m, r0 + per);
        int r = r0;
        for (; r + 8 <= r1; r += 8) {
            u64 p[8];
#pragma unroll
            for (int k = 0; k < 8; ++k) p[k] = stage[r + k];
            float v[8]; int dl[8];
#pragma unroll
            for (int k = 0; k < 8; ++k) {
                unsigned int lo = (unsigned int)p[k];
                dl[k] = (int)(lo & 63u);
                v[k] = __uint_as_float((unsigned int)(p[k] >> 32))
                     * xT[(lo >> 6) * 64 + lane];   // 8 independent 256B gathers
            }
#pragma unroll
            for (int k = 0; k < 8; ++k)
                atomicAdd(&acc[dl[k] * 65 + lane], v[k]);   // ds_add_f32, no return
        }
        for (; r < r1; ++r) {
            u64 p = stage[r];
            unsigned int lo = (unsigned int)p;
            float v = __uint_as_float((unsigned int)(p >> 32)) * xT[(lo >> 6) * 64 + lane];
            atomicAdd(&acc[(lo & 63u) * 65 + lane], v);
        }
        __syncthreads();
    }

    // epilogue: n = g*64 + lane; each of 16 waves writes 4 batch rows, coalesced
    int n = g * 64 + lane;
    float sl = 0.f, bi = 0.f;
    if (n < N) { sl = x[n] * self_w[n]; bi = bias[n]; }  // x row 0 (ref quirk)
#pragma unroll
    for (int i = 0; i < 4; ++i) {
        int b = wave * 4 + i;
        if (n < N) {
            float v = acc[lane * 65 + b] * sl + bi;      // (lane+b)%32: 2-way, free
            out[(long)b * N + n] = fmaxf(v, 0.f);
        }
    }
}

extern "C" void kernel_launch(void* const* d_in, const int* in_sizes, int n_in,
                              void* d_out, int out_size, void* d_ws, size_t ws_size,
                              hipStream_t stream) {
    const float* x      = (const float*)d_in[0];
    const float* adj    = (const float*)d_in[1];
    const float* w      = (const float*)d_in[2];
    const float* self_w = (const float*)d_in[3];
    const float* bias   = (const float*)d_in[4];
    const int*   src    = (const int*)d_in[5];
    const int*   dst    = (const int*)d_in[6];

    int N = in_sizes[3];            // 20000
    int E = in_sizes[1];            // 1,280,000
    (void)n_in; (void)ws_size; (void)out_size;

    int ngroups = (N + 63) / 64;    // 313 (must be <= 511)

    u64*   packed = (u64*)d_ws;                       // E
    float* xT     = (float*)(packed + E);             // N*64
    int*   gcnt   = (int*)(xT + (size_t)N * 64);      // ngroups+1
    int*   goff   = gcnt + 512;                       // ngroups+1
    int*   gcur   = goff + 512;                       // ngroups
    float* out    = (float*)d_out;

    int E4 = E / 4;

    hipLaunchKernelGGL(prep_kernel, dim3(ngroups), dim3(256), 0, stream,
                       x, xT, gcnt, N, ngroups);
    hipLaunchKernelGGL(hist_kernel, dim3((E4 + 511) / 512), dim3(256), 0, stream,
                       dst, gcnt, E4, ngroups);
    hipLaunchKernelGGL(scan_kernel, dim3(1), dim3(512), 0, stream,
                       gcnt, goff, gcur, ngroups, E);
    hipLaunchKernelGGL(scatter_kernel, dim3((E + TILE - 1) / TILE), dim3(512), 0, stream,
                       adj, w, src, dst, gcur, packed, E, ngroups);
    hipLaunchKernelGGL(reduce_kernel, dim3(ngroups), dim3(1024), 0, stream,
                       goff, packed, xT, x, self_w, bias, out, N);
}

// Round 6
// 156.681 us; speedup vs baseline: 5.1369x; 5.1369x over previous
//
#include <hip/hip_runtime.h>

typedef unsigned long long u64;

// B = 64 == wavefront size; lane = batch index throughout.
// Pipeline: prep    (x -> xT[N,64] transpose; zero group counters)
//           hist    (per-block LDS histogram of 313 dst-group counters)
//           scan    (1 block: group counts -> goff[ngroups+1], gcur; noff[N]=E)
//           scatter (bucket sort by 64-node dst-group; LDS-staged coalesced flush)
//           sort2   (1 block/group: in-LDS sort of the group's records by dst,
//                    in-place writeback, per-node offsets noff)
//           reduce  (R3 structure: one wave per node, REGISTER accumulator,
//                    8-deep independent gather batches — NO LDS atomics)

__global__ void prep_kernel(const float* __restrict__ x, float* __restrict__ xT,
                            int* __restrict__ gcnt, int N, int ngroups) {
    __shared__ float tile[64][65];
    int n0 = blockIdx.x * 64;
    int tid = threadIdx.x;
    for (int lin = tid; lin < 64 * 64; lin += 256) {
        int nl = lin & 63, b = lin >> 6;
        int n = n0 + nl;
        tile[b][nl] = (n < N) ? x[(long)b * N + n] : 0.f;
    }
    __syncthreads();
    for (int lin = tid; lin < 64 * 64; lin += 256) {
        int b = lin & 63, nl = lin >> 6;
        int n = n0 + nl;
        if (n < N) xT[(long)n * 64 + b] = tile[b][nl];
    }
    if (blockIdx.x == 0) {
        for (int i = tid; i <= ngroups; i += 256) gcnt[i] = 0;
    }
}

__global__ __launch_bounds__(256) void hist_kernel(const int* __restrict__ dst,
                                                   int* __restrict__ gcnt,
                                                   int E4, int ngroups) {
    __shared__ int h[512];
    int tid = threadIdx.x;
    for (int i = tid; i < ngroups; i += 256) h[i] = 0;
    __syncthreads();
    int base = blockIdx.x * 512;
#pragma unroll
    for (int k = 0; k < 2; ++k) {
        int i4 = base + k * 256 + tid;
        if (i4 < E4) {
            int4 d = ((const int4*)dst)[i4];
            atomicAdd(&h[d.x >> 6], 1);
            atomicAdd(&h[d.y >> 6], 1);
            atomicAdd(&h[d.z >> 6], 1);
            atomicAdd(&h[d.w >> 6], 1);
        }
    }
    __syncthreads();
    for (int i = tid; i < ngroups; i += 256) {
        if (h[i]) atomicAdd(&gcnt[i], h[i]);
    }
}

__global__ __launch_bounds__(512) void scan_kernel(const int* __restrict__ gcnt,
                                                   int* __restrict__ goff,
                                                   int* __restrict__ gcur,
                                                   int* __restrict__ noff,
                                                   int ngroups, int E, int N) {
    __shared__ int sm[512];
    int t = threadIdx.x;
    int c = (t < ngroups) ? gcnt[t] : 0;
    sm[t] = c;
    __syncthreads();
    for (int d = 1; d < 512; d <<= 1) {
        int v = sm[t];
        if (t >= d) v += sm[t - d];
        __syncthreads();
        sm[t] = v;
        __syncthreads();
    }
    if (t < ngroups) {
        int ex = sm[t] - c;
        goff[t] = ex;
        gcur[t] = ex;
    }
    if (t == ngroups) goff[t] = E;
    if (t == 0) noff[N] = E;
}

#define TILE 4096  // 512 threads * 8 edges

__global__ __launch_bounds__(512) void scatter_kernel(
        const float* __restrict__ adj, const float* __restrict__ w,
        const int* __restrict__ src, const int* __restrict__ dst,
        int* __restrict__ gcur, u64* __restrict__ packed, int E, int ngroups) {
    __shared__ int cnt[512];
    __shared__ int ofs[512];
    __shared__ int gbase[512];
    __shared__ int sm[512];
    __shared__ u64 staged[TILE];
    __shared__ unsigned short gof[TILE];

    int t = threadIdx.x;
    int base = blockIdx.x * TILE;
    for (int i = t; i <= ngroups; i += 512) cnt[i] = 0;
    __syncthreads();

    u64 pk[8]; int gk[8]; int rk[8];
#pragma unroll
    for (int k = 0; k < 8; ++k) {
        int e = base + k * 512 + t;
        int g; u64 p;
        if (e < E) {
            int d = dst[e];
            float c = adj[e] * w[e];
            g = d >> 6;
            // record: coef (hi32) | src<<6 | dstLocal (lo32)
            p = ((u64)__float_as_uint(c) << 32)
              | (u64)(((unsigned int)src[e] << 6) | (unsigned int)(d & 63));
        } else {
            g = ngroups; p = 0;
        }
        pk[k] = p; gk[k] = g;
        rk[k] = atomicAdd(&cnt[g], 1);
    }
    __syncthreads();

    int c = (t <= ngroups) ? cnt[t] : 0;
    sm[t] = c;
    __syncthreads();
    for (int d = 1; d < 512; d <<= 1) {
        int v = sm[t];
        if (t >= d) v += sm[t - d];
        __syncthreads();
        sm[t] = v;
        __syncthreads();
    }
    ofs[t] = sm[t] - c;
    if (t < ngroups && c > 0) gbase[t] = atomicAdd(&gcur[t], c);
    __syncthreads();

#pragma unroll
    for (int k = 0; k < 8; ++k) {
        int pos = ofs[gk[k]] + rk[k];
        staged[pos] = pk[k];
        gof[pos] = (unsigned short)gk[k];
    }
    __syncthreads();

#pragma unroll
    for (int k = 0; k < 8; ++k) {
        int i = k * 512 + t;
        int g = gof[i];
        if (g < ngroups) packed[gbase[g] + (i - ofs[g])] = staged[i];
    }
}

#define SCAP 8192  // max records per 64-node group (mean 4090, sigma 64)

__global__ __launch_bounds__(1024) void sort2_kernel(
        const int* __restrict__ goff, u64* __restrict__ packed,
        int* __restrict__ noff, int N) {
    __shared__ u64 rec[SCAP];    // 64 KB
    __shared__ u64 rec2[SCAP];   // 64 KB
    __shared__ int hist[64];
    __shared__ int hoff[65];
    __shared__ int cur[64];
    int tid = threadIdx.x;
    int g = blockIdx.x;
    int s = goff[g], e = goff[g + 1];
    int m = min(e - s, SCAP);
    if (tid < 64) hist[tid] = 0;
    __syncthreads();
    // coalesced load + 64-bin histogram (per-thread LDS atomics, low volume)
    for (int i = tid; i < m; i += 1024) {
        u64 p = packed[s + i];
        rec[i] = p;
        atomicAdd(&hist[(int)(p & 63u)], 1);
    }
    __syncthreads();
    if (tid == 0) {
        int run = 0;
        for (int k = 0; k < 64; ++k) { hoff[k] = run; run += hist[k]; }
        hoff[64] = run;
    }
    __syncthreads();
    if (tid < 64) cur[tid] = hoff[tid];
    __syncthreads();
    // place records in dst order; strip dl, keep (coef<<32 | src)
    for (int i = tid; i < m; i += 1024) {
        u64 p = rec[i];
        int pos = atomicAdd(&cur[(int)(p & 63u)], 1);
        rec2[pos] = (p & 0xFFFFFFFF00000000ull) | (u64)((unsigned int)p >> 6);
    }
    __syncthreads();
    // in-place coalesced writeback (block owns [s,e), all reads done)
    for (int i = tid; i < m; i += 1024) packed[s + i] = rec2[i];
    // per-node CSR starts; node end = next node's start (noff[N]=E set by scan)
    if (tid < 64) {
        int n = g * 64 + tid;
        if (n < N) noff[n] = s + hoff[tid];
    }
}

__global__ __launch_bounds__(512) void reduce_kernel(
        const int* __restrict__ noff, const u64* __restrict__ packed,
        const float* __restrict__ xT, const float* __restrict__ x,
        const float* __restrict__ self_w, const float* __restrict__ bias,
        float* __restrict__ out, int N) {
    int wave = threadIdx.x >> 6;            // 0..7
    int lane = threadIdx.x & 63;            // batch index
    int n = blockIdx.x * 8 + wave;          // one wave per node
    if (n >= N) return;
    int s = __builtin_amdgcn_readfirstlane(noff[n]);
    int e = __builtin_amdgcn_readfirstlane(noff[n + 1]);
    float acc0 = 0.f, acc1 = 0.f;
    int j = s;
    for (; j + 8 <= e; j += 8) {
        u64 p[8];
#pragma unroll
        for (int k = 0; k < 8; ++k) p[k] = packed[j + k];   // wave-uniform
        float g[8];
#pragma unroll
        for (int k = 0; k < 8; ++k) {
            int sk = (int)(unsigned int)p[k];
            float ck = __uint_as_float((unsigned int)(p[k] >> 32));
            g[k] = ck * xT[sk * 64 + lane];  // 8 independent 256B gathers
        }
        acc0 += (g[0] + g[1]) + (g[2] + g[3]);
        acc1 += (g[4] + g[5]) + (g[6] + g[7]);
    }
    for (; j < e; ++j) {
        u64 p = packed[j];
        int sk = (int)(unsigned int)p;
        float ck = __uint_as_float((unsigned int)(p >> 32));
        acc0 += ck * xT[sk * 64 + lane];
    }
    float sl = x[n] * self_w[n];            // self-loop uses x row 0 (ref quirk)
    float v = (acc0 + acc1) * sl + bias[n];
    out[(long)lane * N + n] = fmaxf(v, 0.f);  // 4B stores; L2 write-merge (R3: 5MB)
}

extern "C" void kernel_launch(void* const* d_in, const int* in_sizes, int n_in,
                              void* d_out, int out_size, void* d_ws, size_t ws_size,
                              hipStream_t stream) {
    const float* x      = (const float*)d_in[0];
    const float* adj    = (const float*)d_in[1];
    const float* w      = (const float*)d_in[2];
    const float* self_w = (const float*)d_in[3];
    const float* bias   = (const float*)d_in[4];
    const int*   src    = (const int*)d_in[5];
    const int*   dst    = (const int*)d_in[6];

    int N = in_sizes[3];            // 20000
    int E = in_sizes[1];            // 1,280,000
    (void)n_in; (void)ws_size; (void)out_size;

    int ngroups = (N + 63) / 64;    // 313 (must be <= 511)

    u64*   packed = (u64*)d_ws;                       // E
    float* xT     = (float*)(packed + E);             // N*64
    int*   gcnt   = (int*)(xT + (size_t)N * 64);      // ngroups+1
    int*   goff   = gcnt + 512;                       // ngroups+1
    int*   gcur   = goff + 512;                       // ngroups
    int*   noff   = gcur + 512;                       // N+1
    float* out    = (float*)d_out;

    int E4 = E / 4;

    hipLaunchKernelGGL(prep_kernel, dim3(ngroups), dim3(256), 0, stream,
                       x, xT, gcnt, N, ngroups);
    hipLaunchKernelGGL(hist_kernel, dim3((E4 + 511) / 512), dim3(256), 0, stream,
                       dst, gcnt, E4, ngroups);
    hipLaunchKernelGGL(scan_kernel, dim3(1), dim3(512), 0, stream,
                       gcnt, goff, gcur, noff, ngroups, E, N);
    hipLaunchKernelGGL(scatter_kernel, dim3((E + TILE - 1) / TILE), dim3(512), 0, stream,
                       adj, w, src, dst, gcur, packed, E, ngroups);
    hipLaunchKernelGGL(sort2_kernel, dim3(ngroups), dim3(1024), 0, stream,
                       goff, packed, noff, N);
    hipLaunchKernelGGL(reduce_kernel, dim3((N + 7) / 8), dim3(512), 0, stream,
                       noff, packed, xT, x, self_w, bias, out, N);
}

// Round 7
// 148.423 us; speedup vs baseline: 5.4227x; 1.0556x over previous
//
#include <hip/hip_runtime.h>

typedef unsigned long long u64;

// B = 64 == wavefront size; lane = batch index throughout.
// Groups of 64 destination nodes; ngroups = ceil(N/64) = 313 (<= 511).
// Pipeline: prep    (x -> xT[N,64] transpose; zero group counters)
//           hist    (per-block LDS histogram of dst-group counters)
//           scan    (1 block: group counts -> goff[ngroups+1], gcur)
//           scatter (bucket sort by dst-group; LDS-staged coalesced flush)
//           sortreduce (FUSED, 1 block/group: two-pass bin into LDS by
//                    (dstLocal, src-band) -> wave-per-node REGISTER reduce
//                    from LDS records, src-ascending gathers, coalesced out)
// Lessons encoded: no per-record LDS atomics (R4/R5: ~300cy each);
// register acc + 8-deep independent gathers (R3/R6); run-coalesced
// scatter flushes (R3's 78MB random-write fix).

__global__ void prep_kernel(const float* __restrict__ x, float* __restrict__ xT,
                            int* __restrict__ gcnt, int N, int ngroups) {
    __shared__ float tile[64][65];
    int n0 = blockIdx.x * 64;
    int tid = threadIdx.x;
    for (int lin = tid; lin < 64 * 64; lin += 256) {
        int nl = lin & 63, b = lin >> 6;
        int n = n0 + nl;
        tile[b][nl] = (n < N) ? x[(long)b * N + n] : 0.f;
    }
    __syncthreads();
    for (int lin = tid; lin < 64 * 64; lin += 256) {
        int b = lin & 63, nl = lin >> 6;
        int n = n0 + nl;
        if (n < N) xT[(long)n * 64 + b] = tile[b][nl];
    }
    if (blockIdx.x == 0) {
        for (int i = tid; i <= ngroups; i += 256) gcnt[i] = 0;
    }
}

__global__ __launch_bounds__(256) void hist_kernel(const int* __restrict__ dst,
                                                   int* __restrict__ gcnt,
                                                   int E4, int ngroups) {
    __shared__ int h[512];
    int tid = threadIdx.x;
    for (int i = tid; i < ngroups; i += 256) h[i] = 0;
    __syncthreads();
    int base = blockIdx.x * 512;
#pragma unroll
    for (int k = 0; k < 2; ++k) {
        int i4 = base + k * 256 + tid;
        if (i4 < E4) {
            int4 d = ((const int4*)dst)[i4];
            atomicAdd(&h[d.x >> 6], 1);
            atomicAdd(&h[d.y >> 6], 1);
            atomicAdd(&h[d.z >> 6], 1);
            atomicAdd(&h[d.w >> 6], 1);
        }
    }
    __syncthreads();
    for (int i = tid; i < ngroups; i += 256) {
        if (h[i]) atomicAdd(&gcnt[i], h[i]);
    }
}

__global__ __launch_bounds__(512) void scan_kernel(const int* __restrict__ gcnt,
                                                   int* __restrict__ goff,
                                                   int* __restrict__ gcur,
                                                   int ngroups, int E) {
    __shared__ int sm[512];
    int t = threadIdx.x;
    int c = (t < ngroups) ? gcnt[t] : 0;
    sm[t] = c;
    __syncthreads();
    for (int d = 1; d < 512; d <<= 1) {
        int v = sm[t];
        if (t >= d) v += sm[t - d];
        __syncthreads();
        sm[t] = v;
        __syncthreads();
    }
    if (t < ngroups) {
        int ex = sm[t] - c;
        goff[t] = ex;
        gcur[t] = ex;
    }
    if (t == ngroups) goff[t] = E;
}

#define TILE 4096  // 512 threads * 8 edges

__global__ __launch_bounds__(512) void scatter_kernel(
        const float* __restrict__ adj, const float* __restrict__ w,
        const int* __restrict__ src, const int* __restrict__ dst,
        int* __restrict__ gcur, u64* __restrict__ packed, int E, int ngroups) {
    __shared__ int cnt[512];
    __shared__ int ofs[512];
    __shared__ int gbase[512];
    __shared__ int sm[512];
    __shared__ u64 staged[TILE];
    __shared__ unsigned short gof[TILE];

    int t = threadIdx.x;
    int base = blockIdx.x * TILE;
    for (int i = t; i <= ngroups; i += 512) cnt[i] = 0;
    __syncthreads();

    u64 pk[8]; int gk[8]; int rk[8];
#pragma unroll
    for (int k = 0; k < 8; ++k) {
        int e = base + k * 512 + t;
        int g; u64 p;
        if (e < E) {
            int d = dst[e];
            float c = adj[e] * w[e];
            g = d >> 6;
            // record: coef (hi32) | src<<6 | dstLocal (lo32)
            p = ((u64)__float_as_uint(c) << 32)
              | (u64)(((unsigned int)src[e] << 6) | (unsigned int)(d & 63));
        } else {
            g = ngroups; p = 0;
        }
        pk[k] = p; gk[k] = g;
        rk[k] = atomicAdd(&cnt[g], 1);
    }
    __syncthreads();

    int c = (t <= ngroups) ? cnt[t] : 0;
    sm[t] = c;
    __syncthreads();
    for (int d = 1; d < 512; d <<= 1) {
        int v = sm[t];
        if (t >= d) v += sm[t - d];
        __syncthreads();
        sm[t] = v;
        __syncthreads();
    }
    ofs[t] = sm[t] - c;
    if (t < ngroups && c > 0) gbase[t] = atomicAdd(&gcur[t], c);
    __syncthreads();

#pragma unroll
    for (int k = 0; k < 8; ++k) {
        int pos = ofs[gk[k]] + rk[k];
        staged[pos] = pk[k];
        gof[pos] = (unsigned short)gk[k];
    }
    __syncthreads();

#pragma unroll
    for (int k = 0; k < 8; ++k) {
        int i = k * 512 + t;
        int g = gof[i];
        if (g < ngroups) packed[gbase[g] + (i - ofs[g])] = staged[i];
    }
}

#define SCAP 8192   // records per 64-node group: mean 4090, sigma ~64
#define NB   1024   // bins: dstLocal(64) x src-band(16, src>>11)

__global__ __launch_bounds__(1024) void sortreduce_kernel(
        const int* __restrict__ goff, const u64* __restrict__ packed,
        const float* __restrict__ xT, const float* __restrict__ x,
        const float* __restrict__ self_w, const float* __restrict__ bias,
        float* __restrict__ out, int N) {
    __shared__ u64 rec2[SCAP];       // 64 KB; reused as sacc in epilogue
    __shared__ int hist[NB];         // 4 KB
    __shared__ int hoff[NB + 1];     // 4 KB
    __shared__ int cur[NB];          // 4 KB  -> ~76 KB total: 2 blocks/CU
    int tid = threadIdx.x;
    int g = blockIdx.x;
    int s = goff[g], e = goff[g + 1];
    int m = min(e - s, SCAP);
    hist[tid] = 0;
    __syncthreads();

    // pass 1: histogram of (dl, src-band) keys (coalesced global read)
    for (int i = tid; i < m; i += 1024) {
        u64 p = packed[s + i];
        unsigned int lo = (unsigned int)p;
        int key = (int)((lo & 63u) << 4) | (int)((lo >> 6) >> 11);
        atomicAdd(&hist[key], 1);
    }
    __syncthreads();

    // exclusive scan of 1024 bins (Hillis-Steele in cur)
    int c = hist[tid];
    cur[tid] = c;
    __syncthreads();
    for (int d = 1; d < 1024; d <<= 1) {
        int v = cur[tid];
        if (tid >= d) v += cur[tid - d];
        __syncthreads();
        cur[tid] = v;
        __syncthreads();
    }
    int ex = cur[tid] - c;
    hoff[tid] = ex;
    cur[tid] = ex;
    if (tid == 1023) hoff[NB] = m;
    __syncthreads();

    // pass 2: placement (global re-read, L2-hot); strip dl, keep coef|src
    for (int i = tid; i < m; i += 1024) {
        u64 p = packed[s + i];
        unsigned int lo = (unsigned int)p;
        int key = (int)((lo & 63u) << 4) | (int)((lo >> 6) >> 11);
        int pos = atomicAdd(&cur[key], 1);
        rec2[pos] = (p & 0xFFFFFFFF00000000ull) | (u64)(lo >> 6);
    }
    __syncthreads();

    // reduce: wave owns 4 nodes; register acc; src-ascending 8-deep gathers
    int wave = tid >> 6;             // 0..15
    int lane = tid & 63;             // batch index
    float vals[4];
#pragma unroll
    for (int q = 0; q < 4; ++q) {
        int dl = wave * 4 + q;
        int r0 = hoff[dl << 4];          // wave-uniform LDS broadcast
        int r1 = hoff[(dl << 4) + 16];
        float a0 = 0.f, a1 = 0.f;
        int r = r0;
        for (; r + 8 <= r1; r += 8) {
            u64 p[8];
#pragma unroll
            for (int k = 0; k < 8; ++k) p[k] = rec2[r + k];
            float gg[8];
#pragma unroll
            for (int k = 0; k < 8; ++k) {
                int sk = (int)(unsigned int)p[k];
                float ck = __uint_as_float((unsigned int)(p[k] >> 32));
                gg[k] = ck * xT[sk * 64 + lane];  // 8 independent 256B gathers
            }
            a0 += (gg[0] + gg[1]) + (gg[2] + gg[3]);
            a1 += (gg[4] + gg[5]) + (gg[6] + gg[7]);
        }
        for (; r < r1; ++r) {
            u64 p = rec2[r];
            int sk = (int)(unsigned int)p;
            float ck = __uint_as_float((unsigned int)(p >> 32));
            a0 += ck * xT[sk * 64 + lane];
        }
        vals[q] = a0 + a1;
    }
    __syncthreads();                 // all rec2 reads done; reuse as sacc

    float* sacc = (float*)rec2;      // 64 x 65 floats
#pragma unroll
    for (int q = 0; q < 4; ++q)
        sacc[(wave * 4 + q) * 65 + lane] = vals[q];
    __syncthreads();

    // epilogue: n = g*64 + lane; each wave writes 4 batch rows, coalesced
    int n = g * 64 + lane;
    float sl = 0.f, bi = 0.f;
    if (n < N) { sl = x[n] * self_w[n]; bi = bias[n]; }  // x row 0 (ref quirk)
#pragma unroll
    for (int i = 0; i < 4; ++i) {
        int b = wave * 4 + i;
        if (n < N) {
            float v = sacc[lane * 65 + b] * sl + bi;     // (lane+b)%32: 2-way, free
            out[(long)b * N + n] = fmaxf(v, 0.f);
        }
    }
}

extern "C" void kernel_launch(void* const* d_in, const int* in_sizes, int n_in,
                              void* d_out, int out_size, void* d_ws, size_t ws_size,
                              hipStream_t stream) {
    const float* x      = (const float*)d_in[0];
    const float* adj    = (const float*)d_in[1];
    const float* w      = (const float*)d_in[2];
    const float* self_w = (const float*)d_in[3];
    const float* bias   = (const float*)d_in[4];
    const int*   src    = (const int*)d_in[5];
    const int*   dst    = (const int*)d_in[6];

    int N = in_sizes[3];            // 20000
    int E = in_sizes[1];            // 1,280,000
    (void)n_in; (void)ws_size; (void)out_size;

    int ngroups = (N + 63) / 64;    // 313 (must be <= 511)

    u64*   packed = (u64*)d_ws;                       // E
    float* xT     = (float*)(packed + E);             // N*64
    int*   gcnt   = (int*)(xT + (size_t)N * 64);      // ngroups+1
    int*   goff   = gcnt + 512;                       // ngroups+1
    int*   gcur   = goff + 512;                       // ngroups
    float* out    = (float*)d_out;

    int E4 = E / 4;

    hipLaunchKernelGGL(prep_kernel, dim3(ngroups), dim3(256), 0, stream,
                       x, xT, gcnt, N, ngroups);
    hipLaunchKernelGGL(hist_kernel, dim3((E4 + 511) / 512), dim3(256), 0, stream,
                       dst, gcnt, E4, ngroups);
    hipLaunchKernelGGL(scan_kernel, dim3(1), dim3(512), 0, stream,
                       gcnt, goff, gcur, ngroups, E);
    hipLaunchKernelGGL(scatter_kernel, dim3((E + TILE - 1) / TILE), dim3(512), 0, stream,
                       adj, w, src, dst, gcur, packed, E, ngroups);
    hipLaunchKernelGGL(sortreduce_kernel, dim3(ngroups), dim3(1024), 0, stream,
                       goff, packed, xT, x, self_w, bias, out, N);
}

// Round 8
// 148.106 us; speedup vs baseline: 5.4343x; 1.0021x over previous
//
#include <hip/hip_runtime.h>

typedef unsigned long long u64;

// B = 64 == wavefront size; lane = batch index throughout.
// Groups of 64 destination nodes; ngroups = ceil(N/64) = 313 (<= 511).
// Pipeline: prep    (x -> xTh[N,64] transpose in BF16; zero group counters)
//           hist    (per-block LDS histogram of dst-group counters)
//           scan    (1 block: group counts -> goff[ngroups+1], gcur)
//           scatter (bucket sort by dst-group; LDS-staged coalesced flush)
//           sortreduce (1 block/group: two-pass bin into LDS by
//                    (dstLocal, src-band) -> wave-per-node REGISTER reduce,
//                    BF16 xT gathers (2.56MB: fully L2-resident), coalesced out)
// Lessons encoded: no per-record LDS atomics in accumulate (R4/R5: ~300cy);
// register acc + 8-deep independent gathers (R3/R6); run-coalesced scatter
// flushes (R3's 78MB random-write fix); fp32 xT (5.12MB) thrashed the 4MB
// per-XCD L2 -> bf16 xT fits (R8).

__device__ __forceinline__ unsigned short f32_to_bf16(float f) {
    unsigned int u = __float_as_uint(f);
    // round-to-nearest-even
    u += 0x7FFFu + ((u >> 16) & 1u);
    return (unsigned short)(u >> 16);
}

__global__ void prep_kernel(const float* __restrict__ x, unsigned short* __restrict__ xTh,
                            int* __restrict__ gcnt, int N, int ngroups) {
    __shared__ float tile[64][65];
    int n0 = blockIdx.x * 64;
    int tid = threadIdx.x;
    for (int lin = tid; lin < 64 * 64; lin += 256) {
        int nl = lin & 63, b = lin >> 6;
        int n = n0 + nl;
        tile[b][nl] = (n < N) ? x[(long)b * N + n] : 0.f;
    }
    __syncthreads();
    for (int lin = tid; lin < 64 * 64; lin += 256) {
        int b = lin & 63, nl = lin >> 6;
        int n = n0 + nl;
        if (n < N) xTh[(long)n * 64 + b] = f32_to_bf16(tile[b][nl]);
    }
    if (blockIdx.x == 0) {
        for (int i = tid; i <= ngroups; i += 256) gcnt[i] = 0;
    }
}

__global__ __launch_bounds__(256) void hist_kernel(const int* __restrict__ dst,
                                                   int* __restrict__ gcnt,
                                                   int E4, int ngroups) {
    __shared__ int h[512];
    int tid = threadIdx.x;
    for (int i = tid; i < ngroups; i += 256) h[i] = 0;
    __syncthreads();
    int base = blockIdx.x * 512;
#pragma unroll
    for (int k = 0; k < 2; ++k) {
        int i4 = base + k * 256 + tid;
        if (i4 < E4) {
            int4 d = ((const int4*)dst)[i4];
            atomicAdd(&h[d.x >> 6], 1);
            atomicAdd(&h[d.y >> 6], 1);
            atomicAdd(&h[d.z >> 6], 1);
            atomicAdd(&h[d.w >> 6], 1);
        }
    }
    __syncthreads();
    for (int i = tid; i < ngroups; i += 256) {
        if (h[i]) atomicAdd(&gcnt[i], h[i]);
    }
}

__global__ __launch_bounds__(512) void scan_kernel(const int* __restrict__ gcnt,
                                                   int* __restrict__ goff,
                                                   int* __restrict__ gcur,
                                                   int ngroups, int E) {
    __shared__ int sm[512];
    int t = threadIdx.x;
    int c = (t < ngroups) ? gcnt[t] : 0;
    sm[t] = c;
    __syncthreads();
    for (int d = 1; d < 512; d <<= 1) {
        int v = sm[t];
        if (t >= d) v += sm[t - d];
        __syncthreads();
        sm[t] = v;
        __syncthreads();
    }
    if (t < ngroups) {
        int ex = sm[t] - c;
        goff[t] = ex;
        gcur[t] = ex;
    }
    if (t == ngroups) goff[t] = E;
}

#define TILE 4096  // 512 threads * 8 edges

__global__ __launch_bounds__(512) void scatter_kernel(
        const float* __restrict__ adj, const float* __restrict__ w,
        const int* __restrict__ src, const int* __restrict__ dst,
        int* __restrict__ gcur, u64* __restrict__ packed, int E, int ngroups) {
    __shared__ int cnt[512];
    __shared__ int ofs[512];
    __shared__ int gbase[512];
    __shared__ int sm[512];
    __shared__ u64 staged[TILE];
    __shared__ unsigned short gof[TILE];

    int t = threadIdx.x;
    int base = blockIdx.x * TILE;
    for (int i = t; i <= ngroups; i += 512) cnt[i] = 0;
    __syncthreads();

    u64 pk[8]; int gk[8]; int rk[8];
#pragma unroll
    for (int k = 0; k < 8; ++k) {
        int e = base + k * 512 + t;
        int g; u64 p;
        if (e < E) {
            int d = dst[e];
            float c = adj[e] * w[e];
            g = d >> 6;
            // record: coef (hi32) | src<<6 | dstLocal (lo32)
            p = ((u64)__float_as_uint(c) << 32)
              | (u64)(((unsigned int)src[e] << 6) | (unsigned int)(d & 63));
        } else {
            g = ngroups; p = 0;
        }
        pk[k] = p; gk[k] = g;
        rk[k] = atomicAdd(&cnt[g], 1);
    }
    __syncthreads();

    int c = (t <= ngroups) ? cnt[t] : 0;
    sm[t] = c;
    __syncthreads();
    for (int d = 1; d < 512; d <<= 1) {
        int v = sm[t];
        if (t >= d) v += sm[t - d];
        __syncthreads();
        sm[t] = v;
        __syncthreads();
    }
    ofs[t] = sm[t] - c;
    if (t < ngroups && c > 0) gbase[t] = atomicAdd(&gcur[t], c);
    __syncthreads();

#pragma unroll
    for (int k = 0; k < 8; ++k) {
        int pos = ofs[gk[k]] + rk[k];
        staged[pos] = pk[k];
        gof[pos] = (unsigned short)gk[k];
    }
    __syncthreads();

#pragma unroll
    for (int k = 0; k < 8; ++k) {
        int i = k * 512 + t;
        int g = gof[i];
        if (g < ngroups) packed[gbase[g] + (i - ofs[g])] = staged[i];
    }
}

#define SCAP 8192   // records per 64-node group: mean 4090, sigma ~64
#define NB   1024   // bins: dstLocal(64) x src-band(16, src>>11)

__global__ __launch_bounds__(1024) void sortreduce_kernel(
        const int* __restrict__ goff, const u64* __restrict__ packed,
        const unsigned short* __restrict__ xTh, const float* __restrict__ x,
        const float* __restrict__ self_w, const float* __restrict__ bias,
        float* __restrict__ out, int N) {
    __shared__ u64 rec2[SCAP];       // 64 KB; reused as sacc in epilogue
    __shared__ int hist[NB];         // 4 KB
    __shared__ int hoff[NB + 1];     // 4 KB
    __shared__ int cur[NB];          // 4 KB  -> ~76 KB total: 2 blocks/CU
    int tid = threadIdx.x;
    int g = blockIdx.x;
    int s = goff[g], e = goff[g + 1];
    int m = min(e - s, SCAP);
    hist[tid] = 0;
    __syncthreads();

    // pass 1: histogram of (dl, src-band) keys (coalesced global read)
    for (int i = tid; i < m; i += 1024) {
        u64 p = packed[s + i];
        unsigned int lo = (unsigned int)p;
        int key = (int)((lo & 63u) << 4) | (int)((lo >> 6) >> 11);
        atomicAdd(&hist[key], 1);
    }
    __syncthreads();

    // exclusive scan of 1024 bins (Hillis-Steele in cur)
    int c = hist[tid];
    cur[tid] = c;
    __syncthreads();
    for (int d = 1; d < 1024; d <<= 1) {
        int v = cur[tid];
        if (tid >= d) v += cur[tid - d];
        __syncthreads();
        cur[tid] = v;
        __syncthreads();
    }
    int ex = cur[tid] - c;
    hoff[tid] = ex;
    cur[tid] = ex;
    if (tid == 1023) hoff[NB] = m;
    __syncthreads();

    // pass 2: placement (global re-read, L2-hot); strip dl, keep coef|src
    for (int i = tid; i < m; i += 1024) {
        u64 p = packed[s + i];
        unsigned int lo = (unsigned int)p;
        int key = (int)((lo & 63u) << 4) | (int)((lo >> 6) >> 11);
        int pos = atomicAdd(&cur[key], 1);
        rec2[pos] = (p & 0xFFFFFFFF00000000ull) | (u64)(lo >> 6);
    }
    __syncthreads();

    // reduce: wave owns 4 nodes; register acc; src-ascending 8-deep bf16 gathers
    int wave = tid >> 6;             // 0..15
    int lane = tid & 63;             // batch index
    float vals[4];
#pragma unroll
    for (int q = 0; q < 4; ++q) {
        int dl = wave * 4 + q;
        int r0 = hoff[dl << 4];          // wave-uniform LDS broadcast
        int r1 = hoff[(dl << 4) + 16];
        float a0 = 0.f, a1 = 0.f;
        int r = r0;
        for (; r + 8 <= r1; r += 8) {
            u64 p[8];
#pragma unroll
            for (int k = 0; k < 8; ++k) p[k] = rec2[r + k];
            float gg[8];
#pragma unroll
            for (int k = 0; k < 8; ++k) {
                int sk = (int)(unsigned int)p[k];
                float ck = __uint_as_float((unsigned int)(p[k] >> 32));
                // 8 independent 128B bf16 gathers (xTh L2-resident)
                float xv = __uint_as_float((unsigned int)xTh[sk * 64 + lane] << 16);
                gg[k] = ck * xv;
            }
            a0 += (gg[0] + gg[1]) + (gg[2] + gg[3]);
            a1 += (gg[4] + gg[5]) + (gg[6] + gg[7]);
        }
        for (; r < r1; ++r) {
            u64 p = rec2[r];
            int sk = (int)(unsigned int)p;
            float ck = __uint_as_float((unsigned int)(p >> 32));
            float xv = __uint_as_float((unsigned int)xTh[sk * 64 + lane] << 16);
            a0 += ck * xv;
        }
        vals[q] = a0 + a1;
    }
    __syncthreads();                 // all rec2 reads done; reuse as sacc

    float* sacc = (float*)rec2;      // 64 x 65 floats
#pragma unroll
    for (int q = 0; q < 4; ++q)
        sacc[(wave * 4 + q) * 65 + lane] = vals[q];
    __syncthreads();

    // epilogue: n = g*64 + lane; each wave writes 4 batch rows, coalesced
    int n = g * 64 + lane;
    float sl = 0.f, bi = 0.f;
    if (n < N) { sl = x[n] * self_w[n]; bi = bias[n]; }  // x row 0 (ref quirk)
#pragma unroll
    for (int i = 0; i < 4; ++i) {
        int b = wave * 4 + i;
        if (n < N) {
            float v = sacc[lane * 65 + b] * sl + bi;     // (lane+b)%32: 2-way, free
            out[(long)b * N + n] = fmaxf(v, 0.f);
        }
    }
}

extern "C" void kernel_launch(void* const* d_in, const int* in_sizes, int n_in,
                              void* d_out, int out_size, void* d_ws, size_t ws_size,
                              hipStream_t stream) {
    const float* x      = (const float*)d_in[0];
    const float* adj    = (const float*)d_in[1];
    const float* w      = (const float*)d_in[2];
    const float* self_w = (const float*)d_in[3];
    const float* bias   = (const float*)d_in[4];
    const int*   src    = (const int*)d_in[5];
    const int*   dst    = (const int*)d_in[6];

    int N = in_sizes[3];            // 20000
    int E = in_sizes[1];            // 1,280,000
    (void)n_in; (void)ws_size; (void)out_size;

    int ngroups = (N + 63) / 64;    // 313 (must be <= 511)

    // workspace layout: packed (8B) first, then bf16 xTh, then 4B ints
    u64*            packed = (u64*)d_ws;                        // E
    unsigned short* xTh    = (unsigned short*)(packed + E);     // N*64 (2.56MB)
    int*            gcnt   = (int*)(xTh + (size_t)N * 64);      // ngroups+1
    int*            goff   = gcnt + 512;                        // ngroups+1
    int*            gcur   = goff + 512;                        // ngroups
    float*          out    = (float*)d_out;

    int E4 = E / 4;

    hipLaunchKernelGGL(prep_kernel, dim3(ngroups), dim3(256), 0, stream,
                       x, xTh, gcnt, N, ngroups);
    hipLaunchKernelGGL(hist_kernel, dim3((E4 + 511) / 512), dim3(256), 0, stream,
                       dst, gcnt, E4, ngroups);
    hipLaunchKernelGGL(scan_kernel, dim3(1), dim3(512), 0, stream,
                       gcnt, goff, gcur, ngroups, E);
    hipLaunchKernelGGL(scatter_kernel, dim3((E + TILE - 1) / TILE), dim3(512), 0, stream,
                       adj, w, src, dst, gcur, packed, E, ngroups);
    hipLaunchKernelGGL(sortreduce_kernel, dim3(ngroups), dim3(1024), 0, stream,
                       goff, packed, xTh, x, self_w, bias, out, N);
}

// Round 9
// 125.080 us; speedup vs baseline: 6.4347x; 1.1841x over previous
//
#include <hip/hip_runtime.h>

typedef unsigned long long u64;

// B = 64 == wavefront size; lane = batch index throughout.
// Groups of GSZ=40 destination nodes; NG=500 groups -> grid 500 ~= 2 blocks/CU
// (fixes R8's 313-on-256 straggler-wave imbalance). Fixed-capacity buckets
// (CAP=4096 vs mean fill 2560, 30 sigma) remove the hist+scan kernels.
// Pipeline: prep    (x -> xTh[N,64] bf16 transpose; zero gcur)
//           scatter (bucket by dst-group; LDS-staged run-coalesced flush
//                    into packed[g*CAP + atomic]; no global hist/scan needed)
//           sortreduce (1 block/group: two-pass bin into LDS by
//                    (dstLocal, src-band) -> wave-per-node REGISTER reduce)
// Lessons: no per-record LDS atomics in accumulate (R4/R5 ~300cy); register
// acc + 8-deep independent gathers (R3/R6); run-coalesced scatter flush (R3);
// bf16 xT neutral-but-harmless (R8); grid must match 256 CUs (R9).

#define GSZ 40
#define CAP 4096   // records per group slot; mean 2560, sigma ~51

__device__ __forceinline__ unsigned short f32_to_bf16(float f) {
    unsigned int u = __float_as_uint(f);
    u += 0x7FFFu + ((u >> 16) & 1u);   // round-to-nearest-even
    return (unsigned short)(u >> 16);
}

__global__ void prep_kernel(const float* __restrict__ x, unsigned short* __restrict__ xTh,
                            int* __restrict__ gcur, int N, int ngroups) {
    __shared__ float tile[64][65];
    int n0 = blockIdx.x * 64;
    int tid = threadIdx.x;
    for (int lin = tid; lin < 64 * 64; lin += 256) {
        int nl = lin & 63, b = lin >> 6;
        int n = n0 + nl;
        tile[b][nl] = (n < N) ? x[(long)b * N + n] : 0.f;
    }
    __syncthreads();
    for (int lin = tid; lin < 64 * 64; lin += 256) {
        int b = lin & 63, nl = lin >> 6;
        int n = n0 + nl;
        if (n < N) xTh[(long)n * 64 + b] = f32_to_bf16(tile[b][nl]);
    }
    if (blockIdx.x == 0) {
        for (int i = tid; i < ngroups; i += 256) gcur[i] = 0;
    }
}

#define STILE 2560  // 512 threads * 5 edges

__global__ __launch_bounds__(512) void scatter_kernel(
        const float* __restrict__ adj, const float* __restrict__ w,
        const int* __restrict__ src, const int* __restrict__ dst,
        int* __restrict__ gcur, u64* __restrict__ packed, int E, int ngroups) {
    __shared__ int cnt[512];
    __shared__ int ofs[512];
    __shared__ int gbase[512];
    __shared__ int sm[512];
    __shared__ u64 staged[STILE];           // 20 KB
    __shared__ unsigned short gof[STILE];   // 5 KB

    int t = threadIdx.x;
    int base = blockIdx.x * STILE;
    cnt[t] = 0;
    __syncthreads();

    u64 pk[5]; int gk[5]; int rk[5];
#pragma unroll
    for (int k = 0; k < 5; ++k) {
        int e = base + k * 512 + t;
        int g; u64 p;
        if (e < E) {
            int d = dst[e];
            float c = adj[e] * w[e];
            g = d / GSZ;                    // compiler magic-mul (constant)
            // record: coef (hi32) | src<<6 | dstLocal (lo32); dl<40 fits 6 bits
            p = ((u64)__float_as_uint(c) << 32)
              | (u64)(((unsigned int)src[e] << 6) | (unsigned int)(d - g * GSZ));
        } else {
            g = ngroups; p = 0;
        }
        pk[k] = p; gk[k] = g;
        rk[k] = atomicAdd(&cnt[g], 1);
    }
    __syncthreads();

    // in-block exclusive scan over ngroups+1 bins (padded to 512)
    int c = cnt[t];
    sm[t] = c;
    __syncthreads();
    for (int d = 1; d < 512; d <<= 1) {
        int v = sm[t];
        if (t >= d) v += sm[t - d];
        __syncthreads();
        sm[t] = v;
        __syncthreads();
    }
    ofs[t] = sm[t] - c;
    if (t < ngroups && c > 0) gbase[t] = atomicAdd(&gcur[t], c);
    __syncthreads();

    // stage records ordered by bucket
#pragma unroll
    for (int k = 0; k < 5; ++k) {
        int pos = ofs[gk[k]] + rk[k];
        staged[pos] = pk[k];
        gof[pos] = (unsigned short)gk[k];
    }
    __syncthreads();

    // flush: consecutive i within a bucket-run -> consecutive global dest
#pragma unroll
    for (int k = 0; k < 5; ++k) {
        int i = k * 512 + t;
        int g = gof[i];
        if (g < ngroups) {
            int idx = gbase[g] + (i - ofs[g]);
            if (idx < CAP) packed[(long)g * CAP + idx] = staged[i];
        }
    }
}

#define NB 1024   // bins: dstLocal(<64, 6b) x src-band(4b, src>>11 in 0..9)

__global__ __launch_bounds__(1024) void sortreduce_kernel(
        const int* __restrict__ gcur, const u64* __restrict__ packed,
        const unsigned short* __restrict__ xTh, const float* __restrict__ x,
        const float* __restrict__ self_w, const float* __restrict__ bias,
        float* __restrict__ out, int N) {
    __shared__ u64 rec2[CAP];        // 32 KB; reused as sacc in epilogue
    __shared__ int hist[NB];         // 4 KB
    __shared__ int hoff[NB + 1];     // 4 KB
    __shared__ int cur[NB];          // 4 KB  -> ~44 KB total
    int tid = threadIdx.x;
    int g = blockIdx.x;
    long s = (long)g * CAP;
    int m = min(gcur[g], CAP);
    hist[tid] = 0;
    __syncthreads();

    // pass 1: histogram of (dl, src-band) keys (coalesced global read)
    for (int i = tid; i < m; i += 1024) {
        u64 p = packed[s + i];
        unsigned int lo = (unsigned int)p;
        int key = (int)((lo & 63u) << 4) | (int)((lo >> 6) >> 11);
        atomicAdd(&hist[key], 1);
    }
    __syncthreads();

    // exclusive scan of 1024 bins (Hillis-Steele in cur)
    int c = hist[tid];
    cur[tid] = c;
    __syncthreads();
    for (int d = 1; d < 1024; d <<= 1) {
        int v = cur[tid];
        if (tid >= d) v += cur[tid - d];
        __syncthreads();
        cur[tid] = v;
        __syncthreads();
    }
    int ex = cur[tid] - c;
    hoff[tid] = ex;
    cur[tid] = ex;
    if (tid == 1023) hoff[NB] = m;
    __syncthreads();

    // pass 2: placement (L2-hot re-read); strip dl, keep coef|src
    for (int i = tid; i < m; i += 1024) {
        u64 p = packed[s + i];
        unsigned int lo = (unsigned int)p;
        int key = (int)((lo & 63u) << 4) | (int)((lo >> 6) >> 11);
        int pos = atomicAdd(&cur[key], 1);
        rec2[pos] = (p & 0xFFFFFFFF00000000ull) | (u64)(lo >> 6);
    }
    __syncthreads();

    // reduce: waves cover 40 nodes (stride 16); register acc; 8-deep gathers
    int wave = tid >> 6;             // 0..15
    int lane = tid & 63;             // batch index
    float vals[3];
    int nvals = 0;
    for (int dl = wave; dl < GSZ; dl += 16) {
        int r0 = hoff[dl << 4];          // wave-uniform LDS broadcast
        int r1 = hoff[(dl << 4) + 16];
        float a0 = 0.f, a1 = 0.f;
        int r = r0;
        for (; r + 8 <= r1; r += 8) {
            u64 p[8];
#pragma unroll
            for (int k = 0; k < 8; ++k) p[k] = rec2[r + k];
            float gg[8];
#pragma unroll
            for (int k = 0; k < 8; ++k) {
                int sk = (int)(unsigned int)p[k];
                float ck = __uint_as_float((unsigned int)(p[k] >> 32));
                float xv = __uint_as_float((unsigned int)xTh[sk * 64 + lane] << 16);
                gg[k] = ck * xv;         // 8 independent 128B bf16 gathers
            }
            a0 += (gg[0] + gg[1]) + (gg[2] + gg[3]);
            a1 += (gg[4] + gg[5]) + (gg[6] + gg[7]);
        }
        for (; r < r1; ++r) {
            u64 p = rec2[r];
            int sk = (int)(unsigned int)p;
            float ck = __uint_as_float((unsigned int)(p >> 32));
            float xv = __uint_as_float((unsigned int)xTh[sk * 64 + lane] << 16);
            a0 += ck * xv;
        }
        vals[nvals++] = a0 + a1;
    }
    __syncthreads();                 // all rec2 reads done; reuse as sacc

    float* sacc = (float*)rec2;      // GSZ x 65 floats
    nvals = 0;
    for (int dl = wave; dl < GSZ; dl += 16)
        sacc[dl * 65 + lane] = vals[nvals++];
    __syncthreads();

    // epilogue: each wave writes 4 batch rows; 40 lanes active per row
    int nl = lane;
    int n = g * GSZ + nl;
    float sl = 0.f, bi = 0.f;
    bool ok = (nl < GSZ) && (n < N);
    if (ok) { sl = x[n] * self_w[n]; bi = bias[n]; }   // x row 0 (ref quirk)
#pragma unroll
    for (int i = 0; i < 4; ++i) {
        int b = wave * 4 + i;
        if (ok) {
            float v = sacc[nl * 65 + b] * sl + bi;
            out[(long)b * N + n] = fmaxf(v, 0.f);      // 160B runs, coalesced
        }
    }
}

extern "C" void kernel_launch(void* const* d_in, const int* in_sizes, int n_in,
                              void* d_out, int out_size, void* d_ws, size_t ws_size,
                              hipStream_t stream) {
    const float* x      = (const float*)d_in[0];
    const float* adj    = (const float*)d_in[1];
    const float* w      = (const float*)d_in[2];
    const float* self_w = (const float*)d_in[3];
    const float* bias   = (const float*)d_in[4];
    const int*   src    = (const int*)d_in[5];
    const int*   dst    = (const int*)d_in[6];

    int N = in_sizes[3];            // 20000
    int E = in_sizes[1];            // 1,280,000
    (void)n_in; (void)ws_size; (void)out_size;

    int ngroups = (N + GSZ - 1) / GSZ;   // 500

    // workspace: packed (8B) first, then bf16 xTh, then gcur
    u64*            packed = (u64*)d_ws;                        // NG*CAP (16.4MB)
    unsigned short* xTh    = (unsigned short*)(packed + (size_t)ngroups * CAP);
    int*            gcur   = (int*)(xTh + (size_t)N * 64);      // ngroups
    float*          out    = (float*)d_out;

    int nb_prep = (N + 63) / 64;                   // 313 (prep is tiny)
    int nb_scat = (E + STILE - 1) / STILE;         // 500

    hipLaunchKernelGGL(prep_kernel, dim3(nb_prep), dim3(256), 0, stream,
                       x, xTh, gcur, N, ngroups);
    hipLaunchKernelGGL(scatter_kernel, dim3(nb_scat), dim3(512), 0, stream,
                       adj, w, src, dst, gcur, packed, E, ngroups);
    hipLaunchKernelGGL(sortreduce_kernel, dim3(ngroups), dim3(1024), 0, stream,
                       gcur, packed, xTh, x, self_w, bias, out, N);
}